// Round 13
// baseline (109.194 us; speedup 1.0000x reference)
//
#include <hip/hip_runtime.h>
#include <hip/hip_bf16.h>

// Shapes (fixed)
#define NB 8
#define NT 64
#define NI 256
#define NJ 256
#define ND 256
#define NKD 64
#define NVD 64
#define SCL 0.125f   // 1/sqrt(64), both attention levels

typedef __attribute__((ext_vector_type(4))) float f32x4;
typedef __attribute__((ext_vector_type(8))) short bf16x8;  // 8 bf16 = 4 VGPR (MFMA A/B frag)
typedef __attribute__((ext_vector_type(4))) short bf16x4;  // 4 bf16 = 8 B packed store

// D[16 M][16 N] = A[16 M][32 K] * B[32 K][16 N] + C
// A frag: lane l holds A[l%16][8*(l/16)+e] ; B frag: B[8*(l/16)+e][l%16]
// C/D:    lane l holds D[4*(l/16)+r][l%16]
#define MFMA16(A, B, C) __builtin_amdgcn_mfma_f32_16x16x32_bf16((A), (B), (C), 0, 0, 0)

// LDS (160 KB total):
//   R1 [0,32K):     Wv-hi -> V-hi[64 vd][256 j]   (rows 512 B, blk^(vd&7))
//   XB [32K,160K):  X-bf16[256 j][256 d]          (rows 512 B, blk^(j&7))
#define XB 32768

__device__ __forceinline__ unsigned short f2bf(float x) {   // RNE
  return __builtin_bit_cast(unsigned short, __float2bfloat16(x));
}
__device__ __forceinline__ float bf2f(unsigned short h) {
  return __builtin_bit_cast(float, (unsigned)h << 16);
}
// split fp32 -> hi + lo bf16; hi+lo = x to ~2^-18 rel
__device__ __forceinline__ void split8(const float* __restrict__ x, bf16x8& hi, bf16x8& lo) {
  #pragma unroll
  for (int e = 0; e < 8; ++e) {
    unsigned short h = f2bf(x[e]);
    hi[e] = (short)h;
    lo[e] = (short)f2bf(x[e] - bf2f(h));
  }
}

// =====================================================================
// K1a: blocks 0..255: Wv -> Wv-hi plane [64 vd][256 d] (transposed)
//      blocks 256..2303: Q fp32 = input_seq @ Wq + bq (one row each)
// =====================================================================
__global__ __launch_bounds__(64) void k_prepA(
    const float* __restrict__ x, const float* __restrict__ Wq,
    const float* __restrict__ bq, const float* __restrict__ Wv,
    unsigned short* __restrict__ Wvth, float* __restrict__ Qf) {
  int lane = threadIdx.x;
  if (blockIdx.x < 256) {
    int t = blockIdx.x * 64 + lane;     // 0..16383
    int d = t >> 6, vd = t & 63;
    Wvth[vd * 256 + d] = f2bf(Wv[t]);
    return;
  }
  int row = blockIdx.x - 256;
  __shared__ __align__(16) float xs[ND];
  const float* xr = x + (size_t)row * ND;
  #pragma unroll
  for (int cc = 0; cc < 4; ++cc) xs[lane + 64 * cc] = xr[lane + 64 * cc];
  __syncthreads();
  float acc = bq[lane];
  #pragma unroll 4
  for (int d = 0; d < ND; ++d) acc = fmaf(xs[d], Wq[d * NKD + lane], acc);
  Qf[(size_t)row * NKD + lane] = acc;   // fp32 (consumed by k_prepB)
}

// =====================================================================
// K1b: Qk[bi][d] = sum_kd Wk[d][kd] * Qf[bi][kd]  (bf16 out)
// 256 blocks x 256 thr; block handles 8 bi rows; thread owns one d.
// =====================================================================
__global__ __launch_bounds__(256) void k_prepB(
    const float* __restrict__ Wk, const float* __restrict__ Qf,
    unsigned short* __restrict__ Qkw) {
  __shared__ __align__(16) float qs[8 * 64];
  int tid = threadIdx.x;
  size_t bi0 = (size_t)blockIdx.x * 8;
  qs[tid]       = Qf[bi0 * 64 + tid];
  qs[tid + 256] = Qf[bi0 * 64 + tid + 256];
  __syncthreads();
  int d = tid;
  float acc[8];
  #pragma unroll
  for (int r8 = 0; r8 < 8; ++r8) acc[r8] = 0.f;
  #pragma unroll 4
  for (int kc = 0; kc < 16; ++kc) {
    float4 wv = *(const float4*)(Wk + (size_t)d * 64 + kc * 4);
    #pragma unroll
    for (int r8 = 0; r8 < 8; ++r8) {
      const float* q4 = qs + r8 * 64 + kc * 4;
      acc[r8] += wv.x * q4[0] + wv.y * q4[1] + wv.z * q4[2] + wv.w * q4[3];
    }
  }
  #pragma unroll
  for (int r8 = 0; r8 < 8; ++r8)
    Qkw[(bi0 + r8) * 256 + d] = f2bf(acc[r8]);
}

// =====================================================================
// K2: FUSED per-(b,t). 1024 thr (16 waves), grid 512, LDS 160 KB.
// Wave w: V j-tile = i-tile = w*16..+16.
// Phase 1 (merged): V-proj (Y stream, 2-term vs Wv-hi in R1) INTERLEAVED
//   with X staging (fp32 load -> bf16 -> swizzled ds_write to XB).
//   X path has NO MFMA dependency — pure streaming.
// Phase 2: S^T[j,i] = sum_d X[j,d]*Qk[i,d]  (K-proj DELETED by
//   associativity; bk cancels in both softmaxes exactly).
//   softmax + in-register P redistribution + PV (all R12-verified).
// 3 barriers; LDS read-only after the last -> race-free.
// =====================================================================
__global__ __launch_bounds__(1024) void k_fused(
    const float* __restrict__ Xm, const float* __restrict__ Ym,
    const unsigned short* __restrict__ Wvth, const float* __restrict__ bv,
    const unsigned short* __restrict__ Qkw,
    unsigned short* __restrict__ R,      // [bt][256 i][64 vd] bf16
    float* __restrict__ Sc) {            // [bt][256 i] raw row max (sans Q*bk shift)
  __shared__ __align__(16) char smemb[163840];   // 160 KB
  int tid = threadIdx.x;
  int bt = blockIdx.x, b = bt >> 6;
  int w = tid >> 6, lane = tid & 63, c = lane & 15, g = lane >> 4;

  const float* xbase = Xm + (size_t)bt * 65536;
  const float* yr = Ym + (size_t)bt * 65536 + (size_t)(w * 16 + c) * 256 + g * 8;

  // prefetch Y chunks 0,1 (fly during Wv staging)
  float4 ya0 = *(const float4*)(yr),      ya1 = *(const float4*)(yr + 4);
  float4 yb0 = *(const float4*)(yr + 32), yb1 = *(const float4*)(yr + 36);
  // preload X-stage chunk for ks=0 (chunk id = tid)
  float4 xf0 = *(const float4*)(xbase + (size_t)(tid >> 5) * 256 + (tid & 31) * 8);
  float4 xf1 = *(const float4*)(xbase + (size_t)(tid >> 5) * 256 + (tid & 31) * 8 + 4);

  // ---- stage Wv-hi -> R1 (2048 chunks, 2 sweeps) ----
  #pragma unroll
  for (int it = 0; it < 2; ++it) {
    int qq = tid + it * 1024;
    int r = qq >> 5, pb = qq & 31;
    uint4 v = *(const uint4*)((const char*)Wvth + (size_t)qq * 16);
    *(uint4*)(smemb + r * 512 + ((pb ^ (r & 7)) << 4)) = v;
  }
  __syncthreads();                                   // barrier 1

  // ---------------- Phase 1: V-proj + X staging (8 k-steps) -------------
  f32x4 vacc[4];
  #pragma unroll
  for (int nf = 0; nf < 4; ++nf) vacc[nf] = (f32x4)0.f;

  #pragma unroll
  for (int ks = 0; ks < 8; ++ks) {
    // X-stage: grab current, issue next chunk's loads immediately
    float4 cx0 = xf0, cx1 = xf1;
    int cc = ks * 1024 + tid;
    if (ks < 7) {
      int cn = cc + 1024;
      xf0 = *(const float4*)(xbase + (size_t)(cn >> 5) * 256 + (cn & 31) * 8);
      xf1 = *(const float4*)(xbase + (size_t)(cn >> 5) * 256 + (cn & 31) * 8 + 4);
    }
    // Y consume/reload (2-deep)
    float y0[8];
    if (ks & 1) {
      *(float4*)&y0[0] = yb0; *(float4*)&y0[4] = yb1;
      if (ks < 6) {
        yb0 = *(const float4*)(yr + (ks + 2) * 32);
        yb1 = *(const float4*)(yr + (ks + 2) * 32 + 4);
      }
    } else {
      *(float4*)&y0[0] = ya0; *(float4*)&y0[4] = ya1;
      if (ks < 6) {
        ya0 = *(const float4*)(yr + (ks + 2) * 32);
        ya1 = *(const float4*)(yr + (ks + 2) * 32 + 4);
      }
    }
    // write X chunk (bf16, swizzled)
    {
      int r = cc >> 5, q2 = cc & 31;
      uint4 xw;
      xw.x = (unsigned int)f2bf(cx0.x) | ((unsigned int)f2bf(cx0.y) << 16);
      xw.y = (unsigned int)f2bf(cx0.z) | ((unsigned int)f2bf(cx0.w) << 16);
      xw.z = (unsigned int)f2bf(cx1.x) | ((unsigned int)f2bf(cx1.y) << 16);
      xw.w = (unsigned int)f2bf(cx1.z) | ((unsigned int)f2bf(cx1.w) << 16);
      *(uint4*)(smemb + XB + r * 512 + ((q2 ^ (r & 7)) << 4)) = xw;
    }
    // V MFMAs (2-term)
    {
      bf16x8 a0h, a0l;
      split8(y0, a0h, a0l);
      #pragma unroll
      for (int nf = 0; nf < 4; ++nf) {
        int r = nf * 16 + c;
        int ba = r * 512 + (((ks * 4 + g) ^ (r & 7)) << 4);
        bf16x8 bwh = *(const bf16x8*)(smemb + ba);
        vacc[nf] = MFMA16(a0h, bwh, vacc[nf]);
        vacc[nf] = MFMA16(a0l, bwh, vacc[nf]);
      }
    }
  }
  // prefetch Qk frags (global, L2-hot; fly across barriers)
  bf16x8 qk[8];
  #pragma unroll
  for (int ks = 0; ks < 8; ++ks)
    qk[ks] = *(const bf16x8*)(Qkw + ((size_t)(b * NI + w * 16 + c)) * 256 + ks * 32 + g * 8);
  __syncthreads();                                   // barrier 2 (Wv reads done)

  // ---- V epilogue: V-hi -> R1 (over Wv); element (j = w*16+4g+r, vd) ----
  #pragma unroll
  for (int nf = 0; nf < 4; ++nf) {
    int vd = nf * 16 + c;
    float bs = bv[vd];
    bf16x4 ph;
    #pragma unroll
    for (int r = 0; r < 4; ++r) ph[r] = (short)f2bf(vacc[nf][r] + bs);
    int pb = w * 2 + (g >> 1);
    *(bf16x4*)(smemb + vd * 512 + ((pb ^ (vd & 7)) << 4) + (g & 1) * 8) = ph;
  }
  __syncthreads();                                   // barrier 3: LDS read-only now

  // ---------------- Phase 2: attention (wave w: i = w*16 + c) -----------
  int i = w * 16 + c;

  // S^T = X * Qk^T : sa[jf] holds S^T[j = 16jf+4g+r][i]
  f32x4 sa[16];
  #pragma unroll
  for (int jf = 0; jf < 16; ++jf) sa[jf] = (f32x4)0.f;
  #pragma unroll
  for (int ks = 0; ks < 8; ++ks) {
    #pragma unroll
    for (int jf = 0; jf < 16; ++jf) {
      int r = jf * 16 + c;
      bf16x8 xa = *(const bf16x8*)(smemb + XB + r * 512 + (((ks * 4 + g) ^ (r & 7)) << 4));
      sa[jf] = MFMA16(xa, qk[ks], sa[jf]);
    }
  }

  // softmax over j (lane-local + 2 shfl over g-groups)
  float mx = sa[0][0];
  #pragma unroll
  for (int jf = 0; jf < 16; ++jf)
    #pragma unroll
    for (int r = 0; r < 4; ++r) mx = fmaxf(mx, sa[jf][r]);
  mx = fmaxf(mx, __shfl_xor(mx, 16));
  mx = fmaxf(mx, __shfl_xor(mx, 32));
  if (g == 0) Sc[(size_t)bt * NI + i] = mx;   // raw max (bk-shift cancels in level-2)
  float sum = 0.f;
  #pragma unroll
  for (int jf = 0; jf < 16; ++jf)
    #pragma unroll
    for (int r = 0; r < 4; ++r) {
      float p = __expf((sa[jf][r] - mx) * SCL);
      sa[jf][r] = p;
      sum += p;
    }
  sum += __shfl_xor(sum, 16);
  sum += __shfl_xor(sum, 32);
  float linv = 1.0f / sum;

  // pack P into bf16-pair words: plo/phi[jf] = j {16jf+4g+0,1}/{2,3}
  unsigned int plo[16], phi[16];
  #pragma unroll
  for (int jf = 0; jf < 16; ++jf) {
    plo[jf] = (unsigned int)f2bf(sa[jf][0]) | ((unsigned int)f2bf(sa[jf][1]) << 16);
    phi[jf] = (unsigned int)f2bf(sa[jf][2]) | ((unsigned int)f2bf(sa[jf][3]) << 16);
  }

  // in-register P^T redistribution (verified R4/R6..R12)
  int srcA = c + 32 * (g & 1);
  int srcB = srcA + 16;
  bool hiH = (g >= 2);

  f32x4 racc[4];
  #pragma unroll
  for (int vf = 0; vf < 4; ++vf) racc[vf] = (f32x4)0.f;
  #pragma unroll
  for (int js = 0; js < 8; ++js) {
    int a0 = __shfl((int)plo[2 * js], srcA);
    int a1 = __shfl((int)phi[2 * js], srcA);
    int a2 = __shfl((int)plo[2 * js], srcB);
    int a3 = __shfl((int)phi[2 * js], srcB);
    int b0 = __shfl((int)plo[2 * js + 1], srcA);
    int b1 = __shfl((int)phi[2 * js + 1], srcA);
    int b2 = __shfl((int)plo[2 * js + 1], srcB);
    int b3 = __shfl((int)phi[2 * js + 1], srcB);
    unsigned int pw0 = (unsigned int)(hiH ? b0 : a0);
    unsigned int pw1 = (unsigned int)(hiH ? b1 : a1);
    unsigned int pw2 = (unsigned int)(hiH ? b2 : a2);
    unsigned int pw3 = (unsigned int)(hiH ? b3 : a3);
    uint4 pwv = make_uint4(pw0, pw1, pw2, pw3);
    bf16x8 pf = __builtin_bit_cast(bf16x8, pwv);
    #pragma unroll
    for (int vf = 0; vf < 4; ++vf) {
      int vd = vf * 16 + c;
      int vba = vd * 512 + (((js * 4 + g) ^ (vd & 7)) << 4);
      bf16x8 vh = *(const bf16x8*)(smemb + vba);
      racc[vf] = MFMA16(vh, pf, racc[vf]);
    }
  }

  // write R[bt][i][vd] bf16, normalized; element (vd = vf*16+4g+r, i)
  #pragma unroll
  for (int vf = 0; vf < 4; ++vf) {
    bf16x4 rk;
    #pragma unroll
    for (int r = 0; r < 4; ++r) rk[r] = (short)f2bf(racc[vf][r] * linv);
    *(bf16x4*)(R + ((size_t)bt * NI + i) * NKD + vf * 16 + g * 4) = rk;
  }
}

// =====================================================================
// K3: level-2 attention over t. 256 thr (4 waves), grid 512.
// Wave handles one (b,i); lane = t for softmax, vd for output.
// =====================================================================
__global__ __launch_bounds__(256) void k_level2(
    const float* __restrict__ Sc,         // [bt][256]
    const unsigned short* __restrict__ R, // [bt][256][64] bf16
    float* __restrict__ out) {            // [b][256][64] f32
  int w = threadIdx.x >> 6, lane = threadIdx.x & 63;
  int bi = blockIdx.x * 4 + w;
  int b = bi >> 8, i = bi & 255;
  float sc = Sc[((size_t)b * NT + lane) * NI + i];
  float mx = sc;
  #pragma unroll
  for (int off = 32; off; off >>= 1) mx = fmaxf(mx, __shfl_xor(mx, off));
  float e = __expf((sc - mx) * SCL);
  float sum = e;
  #pragma unroll
  for (int off = 32; off; off >>= 1) sum += __shfl_xor(sum, off);
  float wn = e / sum;
  float acc = 0.f;
  for (int t = 0; t < NT; ++t) {
    float wt = __shfl(wn, t);
    acc = fmaf(wt, bf2f(R[(((size_t)b * NT + t) * NI + i) * NKD + lane]), acc);
  }
  out[((size_t)b * NI + i) * NVD + lane] = acc;
}

// =====================================================================
extern "C" void kernel_launch(void* const* d_in, const int* in_sizes, int n_in,
                              void* d_out, int out_size, void* d_ws, size_t ws_size,
                              hipStream_t stream) {
  const float* x   = (const float*)d_in[0];
  const float* mxp = (const float*)d_in[1];
  const float* myp = (const float*)d_in[2];
  const float* Wq  = (const float*)d_in[3];
  const float* bq  = (const float*)d_in[4];
  const float* Wk  = (const float*)d_in[5];
  // bk (d_in[6]) cancels exactly in both softmaxes — unused.
  const float* Wv  = (const float*)d_in[7];
  const float* bv  = (const float*)d_in[8];
  float* out = (float*)d_out;

  // workspace carve (~18.5 MB)
  char* p = (char*)d_ws;
  auto alloc = [&](size_t bytes) { char* r = p; p += (bytes + 255) & ~(size_t)255; return r; };
  float*          Qfw  = (float*)alloc((size_t)2048 * 64 * 4);
  unsigned short* Qkw  = (unsigned short*)alloc((size_t)2048 * 256 * 2);
  unsigned short* Rw   = (unsigned short*)alloc((size_t)131072 * 64 * 2);
  float*          Scw  = (float*)alloc((size_t)131072 * 4);
  unsigned short* Wvth = (unsigned short*)alloc(64 * 256 * 2);

  hipLaunchKernelGGL(k_prepA, dim3(256 + NB * NI), dim3(64), 0, stream,
                     x, Wq, bq, Wv, Wvth, Qfw);
  hipLaunchKernelGGL(k_prepB, dim3(256), dim3(256), 0, stream, Wk, Qfw, Qkw);
  hipLaunchKernelGGL(k_fused, dim3(NB * NT), dim3(1024), 0, stream,
                     mxp, myp, Wvth, bv, Qkw, Rw, Scw);
  hipLaunchKernelGGL(k_level2, dim3(512), dim3(256), 0, stream, Scw, Rw, out);
}

// Round 14
// 88.898 us; speedup vs baseline: 1.2283x; 1.2283x over previous
//
#include <hip/hip_runtime.h>
#include <hip/hip_bf16.h>

// Shapes (fixed)
#define NB 8
#define NT 64
#define NI 256
#define NJ 256
#define ND 256
#define NKD 64
#define NVD 64
#define SCL 0.125f   // 1/sqrt(64), both attention levels

typedef __attribute__((ext_vector_type(4))) float f32x4;
typedef __attribute__((ext_vector_type(8))) short bf16x8;  // 8 bf16 = 4 VGPR (MFMA A/B frag)
typedef __attribute__((ext_vector_type(4))) short bf16x4;  // 4 bf16 = 8 B packed store
typedef __attribute__((ext_vector_type(4))) unsigned int uint32x4;

// D[16 M][16 N] = A[16 M][32 K] * B[32 K][16 N] + C
// A frag: lane l holds A[l%16][8*(l/16)+e] ; B frag: B[8*(l/16)+e][l%16]
// C/D:    lane l holds D[4*(l/16)+r][l%16]
#define MFMA16(A, B, C) __builtin_amdgcn_mfma_f32_16x16x32_bf16((A), (B), (C), 0, 0, 0)

// LDS overlay (64 KB total):
//   R1 [0,32K):    Wk-hi -> K-hi[256 j][64 kd]  (rows 128 B, blk^(j&7))
//   R2 [32K,64K):  Wv-hi -> V-hi[64 vd][256 j]  (rows 512 B, blk^(vd&7))
#define R2B 32768

__device__ __forceinline__ unsigned short f2bf(float x) {   // RNE
  return __builtin_bit_cast(unsigned short, __float2bfloat16(x));
}
__device__ __forceinline__ float bf2f(unsigned short h) {
  return __builtin_bit_cast(float, (unsigned)h << 16);
}
// split fp32 -> hi + lo bf16; hi+lo = x to ~2^-18 rel
__device__ __forceinline__ void split8(const float* __restrict__ x, bf16x8& hi, bf16x8& lo) {
  #pragma unroll
  for (int e = 0; e < 8; ++e) {
    unsigned short h = f2bf(x[e]);
    hi[e] = (short)h;
    lo[e] = (short)f2bf(x[e] - bf2f(h));
  }
}

// =====================================================================
// K1: Q-proj (blocks 0..127, 16 rows each, Wq staged in LDS) +
//     W-prep (blocks 128..135). 256 thr.
// 4-partial accumulators break the 256-deep fmaf dependency chain
// (R12's 64-thr serial-chain version was ~10 us, latency-bound).
// =====================================================================
__global__ __launch_bounds__(256) void k_prep_projq(
    const float* __restrict__ x, const float* __restrict__ Wq,
    const float* __restrict__ bq,
    const float* __restrict__ Wk, const float* __restrict__ Wv,
    unsigned short* __restrict__ Wkth, unsigned short* __restrict__ Wvth,
    unsigned short* __restrict__ Qh) {
  int tid = threadIdx.x;
  if (blockIdx.x >= 128) {              // prep weights (hi planes only)
    int t0 = (blockIdx.x - 128) * 2048 + tid * 8;
    #pragma unroll
    for (int e = 0; e < 8; ++e) {
      int t = t0 + e;
      int d = t >> 6, kd = t & 63;
      Wkth[kd * 256 + d] = f2bf(Wk[t]);
      Wvth[kd * 256 + d] = f2bf(Wv[t]);
    }
    return;
  }
  // Q-proj: 16 rows per block; Wq (64 KB) + x rows (16 KB) in LDS
  __shared__ __align__(16) float wqs[256 * 64];
  __shared__ __align__(16) float xs[16 * 256];
  #pragma unroll 8
  for (int it = 0; it < 64; ++it)
    wqs[tid + it * 256] = Wq[tid + it * 256];
  int r0 = blockIdx.x * 16;
  #pragma unroll
  for (int it = 0; it < 16; ++it)
    xs[tid + it * 256] = x[(size_t)r0 * 256 + tid + it * 256];
  __syncthreads();
  int kd = tid & 63, rr = tid >> 6;     // 4 rows per pass, 4 passes
  #pragma unroll
  for (int rp = 0; rp < 4; ++rp) {
    int r = rp * 4 + rr;
    float a0 = bq[kd], a1 = 0.f, a2 = 0.f, a3 = 0.f;
    #pragma unroll 4
    for (int d = 0; d < 256; d += 4) {
      a0 = fmaf(xs[r * 256 + d],     wqs[(d)     * 64 + kd], a0);
      a1 = fmaf(xs[r * 256 + d + 1], wqs[(d + 1) * 64 + kd], a1);
      a2 = fmaf(xs[r * 256 + d + 2], wqs[(d + 2) * 64 + kd], a2);
      a3 = fmaf(xs[r * 256 + d + 3], wqs[(d + 3) * 64 + kd], a3);
    }
    Qh[(size_t)(r0 + r) * 64 + kd] = f2bf((a0 + a1) + (a2 + a3));
  }
}

// =====================================================================
// Single W-plane staging: row r (=kd) is 512 B = 32 16B-chunks,
// swizzle blk ^ (r&7). Fragment read: row f*16+c, chunk ks*4+g.
// =====================================================================
__device__ __forceinline__ void stage_plane(
    char* dstb, const unsigned short* __restrict__ Wt, int tid) {
  #pragma unroll
  for (int it = 0; it < 4; ++it) {
    int qq = tid + it * 512;            // 16B chunk id, 0..2047
    int r = qq >> 5, pb = qq & 31;
    uint4 v = *(const uint4*)((const char*)Wt + (size_t)qq * 16);
    *(uint4*)(dstb + r * 512 + ((pb ^ (r & 7)) << 4)) = v;
  }
}

// =====================================================================
// K2: FUSED per-(b,t), 64 KB LDS, 512 thr (8 waves), grid 512,
// 2 blocks/CU. R12-VERBATIM (best-proven 94.7 us state).
// Merged K/V projection loop; 3 barriers; after the last one LDS is
// read-only (in-register P redistribution) -> race-free.
// Precision: K 2-term (Xhi+Xlo vs Wk-hi), V 2-term (Yhi+Ylo vs Wv-hi),
// S 1-term (K vs Qh), PV 1-term. NO setprio (R11 post-mortem).
// =====================================================================
__global__ __launch_bounds__(512, 4) void k_fused(
    const float* __restrict__ Xm, const float* __restrict__ Ym,
    const unsigned short* __restrict__ Wkth, const unsigned short* __restrict__ Wvth,
    const float* __restrict__ bk, const float* __restrict__ bv,
    const unsigned short* __restrict__ Qh,
    unsigned short* __restrict__ R,      // [bt][256 i][64 vd] bf16
    float* __restrict__ Sc) {            // [bt][256 i] raw row max
  __shared__ __align__(16) char smemb[65536];   // 64 KB
  int tid = threadIdx.x;
  int bt = blockIdx.x, b = bt >> 6;
  int w = tid >> 6, lane = tid & 63, c = lane & 15, g = lane >> 4;

  const float* xr0 = Xm + (size_t)bt * 65536 + (size_t)(w * 32 + c) * 256 + g * 8;
  const float* xr1 = xr0 + 16 * 256;
  const float* yr0 = Ym + (size_t)bt * 65536 + (size_t)(w * 32 + c) * 256 + g * 8;
  const float* yr1 = yr0 + 16 * 256;

  // ---- pre-issue chunks 0,1 of BOTH streams (fly during W staging) ----
  float4 xa0 = *(const float4*)(xr0),      xa1 = *(const float4*)(xr0 + 4);
  float4 xa2 = *(const float4*)(xr1),      xa3 = *(const float4*)(xr1 + 4);
  float4 xb0 = *(const float4*)(xr0 + 32), xb1 = *(const float4*)(xr0 + 36);
  float4 xb2 = *(const float4*)(xr1 + 32), xb3 = *(const float4*)(xr1 + 36);
  float4 ya0 = *(const float4*)(yr0),      ya1 = *(const float4*)(yr0 + 4);
  float4 ya2 = *(const float4*)(yr1),      ya3 = *(const float4*)(yr1 + 4);
  float4 yb0 = *(const float4*)(yr0 + 32), yb1 = *(const float4*)(yr0 + 36);
  float4 yb2 = *(const float4*)(yr1 + 32), yb3 = *(const float4*)(yr1 + 36);

  // ---- stage Wk-hi -> R1, Wv-hi -> R2 ----
  stage_plane(smemb, Wkth, tid);
  stage_plane(smemb + R2B, Wvth, tid);
  __syncthreads();                                   // barrier 1

  // ---------------- merged projection loop (8 k-steps) ------------------
  f32x4 kacc[4][2];   // K: M=kd (4 mf), N=j (2 nj)
  f32x4 vacc[2][4];   // V: M=j (2 mf), N=vd (4 nf)
  #pragma unroll
  for (int mf = 0; mf < 4; ++mf) { kacc[mf][0] = (f32x4)0.f; kacc[mf][1] = (f32x4)0.f; }
  #pragma unroll
  for (int mf = 0; mf < 2; ++mf)
    #pragma unroll
    for (int nf = 0; nf < 4; ++nf) vacc[mf][nf] = (f32x4)0.f;

  #pragma unroll
  for (int ks = 0; ks < 8; ++ks) {
    // ---- X part: consume slot, reload with chunk ks+2, K MFMAs ----
    float x0[8], x1[8];
    if (ks & 1) {
      *(float4*)&x0[0] = xb0; *(float4*)&x0[4] = xb1;
      *(float4*)&x1[0] = xb2; *(float4*)&x1[4] = xb3;
      if (ks < 6) {
        xb0 = *(const float4*)(xr0 + (ks + 2) * 32);
        xb1 = *(const float4*)(xr0 + (ks + 2) * 32 + 4);
        xb2 = *(const float4*)(xr1 + (ks + 2) * 32);
        xb3 = *(const float4*)(xr1 + (ks + 2) * 32 + 4);
      }
    } else {
      *(float4*)&x0[0] = xa0; *(float4*)&x0[4] = xa1;
      *(float4*)&x1[0] = xa2; *(float4*)&x1[4] = xa3;
      if (ks < 6) {
        xa0 = *(const float4*)(xr0 + (ks + 2) * 32);
        xa1 = *(const float4*)(xr0 + (ks + 2) * 32 + 4);
        xa2 = *(const float4*)(xr1 + (ks + 2) * 32);
        xa3 = *(const float4*)(xr1 + (ks + 2) * 32 + 4);
      }
    }
    {
      bf16x8 b0h, b0l, b1h, b1l;
      split8(x0, b0h, b0l);
      split8(x1, b1h, b1l);
      #pragma unroll
      for (int mf = 0; mf < 4; ++mf) {
        int r = mf * 16 + c;
        int ba = r * 512 + (((ks * 4 + g) ^ (r & 7)) << 4);
        bf16x8 awh = *(const bf16x8*)(smemb + ba);
        kacc[mf][0] = MFMA16(awh, b0h, kacc[mf][0]);
        kacc[mf][0] = MFMA16(awh, b0l, kacc[mf][0]);
        kacc[mf][1] = MFMA16(awh, b1h, kacc[mf][1]);
        kacc[mf][1] = MFMA16(awh, b1l, kacc[mf][1]);
      }
    }
    // ---- Y part: consume slot, reload with chunk ks+2, V MFMAs ----
    float y0[8], y1[8];
    if (ks & 1) {
      *(float4*)&y0[0] = yb0; *(float4*)&y0[4] = yb1;
      *(float4*)&y1[0] = yb2; *(float4*)&y1[4] = yb3;
      if (ks < 6) {
        yb0 = *(const float4*)(yr0 + (ks + 2) * 32);
        yb1 = *(const float4*)(yr0 + (ks + 2) * 32 + 4);
        yb2 = *(const float4*)(yr1 + (ks + 2) * 32);
        yb3 = *(const float4*)(yr1 + (ks + 2) * 32 + 4);
      }
    } else {
      *(float4*)&y0[0] = ya0; *(float4*)&y0[4] = ya1;
      *(float4*)&y1[0] = ya2; *(float4*)&y1[4] = ya3;
      if (ks < 6) {
        ya0 = *(const float4*)(yr0 + (ks + 2) * 32);
        ya1 = *(const float4*)(yr0 + (ks + 2) * 32 + 4);
        ya2 = *(const float4*)(yr1 + (ks + 2) * 32);
        ya3 = *(const float4*)(yr1 + (ks + 2) * 32 + 4);
      }
    }
    {
      bf16x8 a0h, a0l, a1h, a1l;
      split8(y0, a0h, a0l);
      split8(y1, a1h, a1l);
      #pragma unroll
      for (int nf = 0; nf < 4; ++nf) {
        int r = nf * 16 + c;
        int ba = R2B + r * 512 + (((ks * 4 + g) ^ (r & 7)) << 4);
        bf16x8 bwh = *(const bf16x8*)(smemb + ba);
        vacc[0][nf] = MFMA16(a0h, bwh, vacc[0][nf]);
        vacc[0][nf] = MFMA16(a0l, bwh, vacc[0][nf]);
        vacc[1][nf] = MFMA16(a1h, bwh, vacc[1][nf]);
        vacc[1][nf] = MFMA16(a1l, bwh, vacc[1][nf]);
      }
    }
  }
  // pre-issue Q frags (fly across the next two barriers)
  bf16x8 qbh[2][2];   // [ks][ic]
  #pragma unroll
  for (int ks = 0; ks < 2; ++ks)
    #pragma unroll
    for (int ic = 0; ic < 2; ++ic) {
      size_t qo = ((size_t)b * NI + w * 32 + ic * 16 + c) * NKD + ks * 32 + g * 8;
      qbh[ks][ic] = *(const bf16x8*)(Qh + qo);
    }
  __syncthreads();                                   // barrier 2 (W reads done)

  // ---- epilogues: K-hi -> R1 (over Wk), V-hi -> R2 (over Wv) ----
  #pragma unroll
  for (int nf = 0; nf < 2; ++nf) {
    int j = w * 32 + nf * 16 + c;
    #pragma unroll
    for (int mf = 0; mf < 4; ++mf) {   // element (kd = mf*16+4g+r, j)
      bf16x4 ph;
      #pragma unroll
      for (int r = 0; r < 4; ++r)
        ph[r] = (short)f2bf(kacc[mf][nf][r] + bk[mf * 16 + g * 4 + r]);
      int pb = mf * 2 + (g >> 1);
      int ba = j * 128 + ((pb ^ (j & 7)) << 4) + (g & 1) * 8;
      *(bf16x4*)(smemb + ba) = ph;
    }
  }
  #pragma unroll
  for (int nf = 0; nf < 4; ++nf) {
    int vd = nf * 16 + c;
    float bs = bv[vd];
    #pragma unroll
    for (int mf = 0; mf < 2; ++mf) {   // element (j = w*32+mf*16+4g+r, vd)
      bf16x4 ph;
      #pragma unroll
      for (int r = 0; r < 4; ++r) ph[r] = (short)f2bf(vacc[mf][nf][r] + bs);
      int pb = w * 4 + mf * 2 + (g >> 1);
      int ba = R2B + vd * 512 + ((pb ^ (vd & 7)) << 4) + (g & 1) * 8;
      *(bf16x4*)(smemb + ba) = ph;
    }
  }
  __syncthreads();                                   // barrier 3: LDS read-only now

  // ---------------- attention (wave w: i = w*32 .. +32) -----------------
  #pragma unroll
  for (int ic = 0; ic < 2; ++ic) {
    int i = w * 32 + ic * 16 + c;

    // S^T = K * Q^T (1 Q-term): sa[jf] holds S^T[j = 16jf+4g+r][i]
    f32x4 sa[16];
    #pragma unroll
    for (int jf = 0; jf < 16; ++jf) sa[jf] = (f32x4)0.f;
    #pragma unroll
    for (int jf = 0; jf < 16; ++jf) {
      int j = jf * 16 + c;
      #pragma unroll
      for (int ks = 0; ks < 2; ++ks) {
        int ba = j * 128 + (((ks * 4 + g) ^ (j & 7)) << 4);
        bf16x8 kh = *(const bf16x8*)(smemb + ba);
        sa[jf] = MFMA16(kh, qbh[ks][ic], sa[jf]);
      }
    }

    // softmax over j (lane-local + 2 shfl)
    float mx = sa[0][0];
    #pragma unroll
    for (int jf = 0; jf < 16; ++jf)
      #pragma unroll
      for (int r = 0; r < 4; ++r) mx = fmaxf(mx, sa[jf][r]);
    mx = fmaxf(mx, __shfl_xor(mx, 16));
    mx = fmaxf(mx, __shfl_xor(mx, 32));
    if (g == 0) Sc[(size_t)bt * NI + i] = mx;   // raw max
    float sum = 0.f;
    #pragma unroll
    for (int jf = 0; jf < 16; ++jf)
      #pragma unroll
      for (int r = 0; r < 4; ++r) {
        float p = __expf((sa[jf][r] - mx) * SCL);
        sa[jf][r] = p;
        sum += p;
      }
    sum += __shfl_xor(sum, 16);
    sum += __shfl_xor(sum, 32);
    float linv = 1.0f / sum;

    // pack P into bf16-pair words: plo/phi[jf] = j {16jf+4g+0,1}/{2,3}
    unsigned int plo[16], phi[16];
    #pragma unroll
    for (int jf = 0; jf < 16; ++jf) {
      plo[jf] = (unsigned int)f2bf(sa[jf][0]) | ((unsigned int)f2bf(sa[jf][1]) << 16);
      phi[jf] = (unsigned int)f2bf(sa[jf][2]) | ((unsigned int)f2bf(sa[jf][3]) << 16);
    }

    // in-register P^T redistribution (verified R4/R6..R12)
    int srcA = c + 32 * (g & 1);
    int srcB = srcA + 16;
    bool hiH = (g >= 2);

    f32x4 racc[4];
    #pragma unroll
    for (int vf = 0; vf < 4; ++vf) racc[vf] = (f32x4)0.f;
    #pragma unroll
    for (int js = 0; js < 8; ++js) {
      int a0 = __shfl((int)plo[2 * js], srcA);
      int a1 = __shfl((int)phi[2 * js], srcA);
      int a2 = __shfl((int)plo[2 * js], srcB);
      int a3 = __shfl((int)phi[2 * js], srcB);
      int b0 = __shfl((int)plo[2 * js + 1], srcA);
      int b1 = __shfl((int)phi[2 * js + 1], srcA);
      int b2 = __shfl((int)plo[2 * js + 1], srcB);
      int b3 = __shfl((int)phi[2 * js + 1], srcB);
      uint32x4 pw;
      pw[0] = (unsigned int)(hiH ? b0 : a0);
      pw[1] = (unsigned int)(hiH ? b1 : a1);
      pw[2] = (unsigned int)(hiH ? b2 : a2);
      pw[3] = (unsigned int)(hiH ? b3 : a3);
      bf16x8 pf = __builtin_bit_cast(bf16x8, pw);
      #pragma unroll
      for (int vf = 0; vf < 4; ++vf) {
        int vd = vf * 16 + c;
        int vba = R2B + vd * 512 + (((js * 4 + g) ^ (vd & 7)) << 4);
        bf16x8 vh = *(const bf16x8*)(smemb + vba);
        racc[vf] = MFMA16(vh, pf, racc[vf]);
      }
    }

    // write R[bt][i][vd] bf16, normalized; element (vd = vf*16+4g+r, i)
    #pragma unroll
    for (int vf = 0; vf < 4; ++vf) {
      bf16x4 rk;
      #pragma unroll
      for (int r = 0; r < 4; ++r) rk[r] = (short)f2bf(racc[vf][r] * linv);
      *(bf16x4*)(R + ((size_t)bt * NI + i) * NKD + vf * 16 + g * 4) = rk;
    }
  }
}

// =====================================================================
// K3: level-2 attention over t. 256 thr (4 waves), grid 512.
// Wave handles one (b,i); lane = t for softmax, vd for output.
// =====================================================================
__global__ __launch_bounds__(256) void k_level2(
    const float* __restrict__ Sc,         // [bt][256]
    const unsigned short* __restrict__ R, // [bt][256][64] bf16
    float* __restrict__ out) {            // [b][256][64] f32
  int w = threadIdx.x >> 6, lane = threadIdx.x & 63;
  int bi = blockIdx.x * 4 + w;
  int b = bi >> 8, i = bi & 255;
  float sc = Sc[((size_t)b * NT + lane) * NI + i];
  float mx = sc;
  #pragma unroll
  for (int off = 32; off; off >>= 1) mx = fmaxf(mx, __shfl_xor(mx, off));
  float e = __expf((sc - mx) * SCL);
  float sum = e;
  #pragma unroll
  for (int off = 32; off; off >>= 1) sum += __shfl_xor(sum, off);
  float wn = e / sum;
  float acc = 0.f;
  for (int t = 0; t < NT; ++t) {
    float wt = __shfl(wn, t);
    acc = fmaf(wt, bf2f(R[(((size_t)b * NT + t) * NI + i) * NKD + lane]), acc);
  }
  out[((size_t)b * NI + i) * NVD + lane] = acc;
}

// =====================================================================
extern "C" void kernel_launch(void* const* d_in, const int* in_sizes, int n_in,
                              void* d_out, int out_size, void* d_ws, size_t ws_size,
                              hipStream_t stream) {
  const float* x   = (const float*)d_in[0];
  const float* mxp = (const float*)d_in[1];
  const float* myp = (const float*)d_in[2];
  const float* Wq  = (const float*)d_in[3];
  const float* bq  = (const float*)d_in[4];
  const float* Wk  = (const float*)d_in[5];
  const float* bk  = (const float*)d_in[6];
  const float* Wv  = (const float*)d_in[7];
  const float* bv  = (const float*)d_in[8];
  float* out = (float*)d_out;

  // workspace carve (~18 MB)
  char* p = (char*)d_ws;
  auto alloc = [&](size_t bytes) { char* r = p; p += (bytes + 255) & ~(size_t)255; return r; };
  unsigned short* Qh   = (unsigned short*)alloc(2048 * 64 * 2);
  unsigned short* Rw   = (unsigned short*)alloc((size_t)131072 * 64 * 2);
  float*          Scw  = (float*)alloc((size_t)131072 * 4);
  unsigned short* Wkth = (unsigned short*)alloc(64 * 256 * 2);
  unsigned short* Wvth = (unsigned short*)alloc(64 * 256 * 2);

  hipLaunchKernelGGL(k_prep_projq, dim3(136), dim3(256), 0, stream,
                     x, Wq, bq, Wk, Wv, Wkth, Wvth, Qh);
  hipLaunchKernelGGL(k_fused, dim3(NB * NT), dim3(512), 0, stream,
                     mxp, myp, Wkth, Wvth, bk, bv, Qh, Rw, Scw);
  hipLaunchKernelGGL(k_level2, dim3(512), dim3(256), 0, stream, Scw, Rw, out);
}

// Round 15
// 85.993 us; speedup vs baseline: 1.2698x; 1.0338x over previous
//
#include <hip/hip_runtime.h>
#include <hip/hip_bf16.h>

// Shapes (fixed)
#define NB 8
#define NT 64
#define NI 256
#define NJ 256
#define ND 256
#define NKD 64
#define NVD 64
#define SCL 0.125f   // 1/sqrt(64), both attention levels

typedef __attribute__((ext_vector_type(4))) float f32x4;
typedef __attribute__((ext_vector_type(8))) short bf16x8;  // 8 bf16 = 4 VGPR (MFMA A/B frag)
typedef __attribute__((ext_vector_type(4))) short bf16x4;  // 4 bf16 = 8 B packed store
typedef __attribute__((ext_vector_type(4))) unsigned int uint32x4;

// D[16 M][16 N] = A[16 M][32 K] * B[32 K][16 N] + C
// A frag: lane l holds A[l%16][8*(l/16)+e] ; B frag: B[8*(l/16)+e][l%16]
// C/D:    lane l holds D[4*(l/16)+r][l%16]
#define MFMA16(A, B, C) __builtin_amdgcn_mfma_f32_16x16x32_bf16((A), (B), (C), 0, 0, 0)

// LDS overlay (64 KB total):
//   R1 [0,32K):    Wk-hi -> K-hi[256 j][64 kd]  (rows 128 B, blk^(j&7))
//   R2 [32K,64K):  Wv-hi -> V-hi[64 vd][256 j]  (rows 512 B, blk^(vd&7))
#define R2B 32768

__device__ __forceinline__ unsigned short f2bf(float x) {   // RNE
  return __builtin_bit_cast(unsigned short, __float2bfloat16(x));
}
__device__ __forceinline__ float bf2f(unsigned short h) {
  return __builtin_bit_cast(float, (unsigned)h << 16);
}
// split fp32 -> hi + lo bf16; hi+lo = x to ~2^-18 rel
__device__ __forceinline__ void split8(const float* __restrict__ x, bf16x8& hi, bf16x8& lo) {
  #pragma unroll
  for (int e = 0; e < 8; ++e) {
    unsigned short h = f2bf(x[e]);
    hi[e] = (short)h;
    lo[e] = (short)f2bf(x[e] - bf2f(h));
  }
}

// =====================================================================
// K1: Q-proj (blocks 0..127, 16 rows each, Wq staged in LDS) +
//     W-prep (blocks 128..135). 256 thr. (R14-verbatim)
// =====================================================================
__global__ __launch_bounds__(256) void k_prep_projq(
    const float* __restrict__ x, const float* __restrict__ Wq,
    const float* __restrict__ bq,
    const float* __restrict__ Wk, const float* __restrict__ Wv,
    unsigned short* __restrict__ Wkth, unsigned short* __restrict__ Wvth,
    unsigned short* __restrict__ Qh) {
  int tid = threadIdx.x;
  if (blockIdx.x >= 128) {              // prep weights (hi planes only)
    int t0 = (blockIdx.x - 128) * 2048 + tid * 8;
    #pragma unroll
    for (int e = 0; e < 8; ++e) {
      int t = t0 + e;
      int d = t >> 6, kd = t & 63;
      Wkth[kd * 256 + d] = f2bf(Wk[t]);
      Wvth[kd * 256 + d] = f2bf(Wv[t]);
    }
    return;
  }
  // Q-proj: 16 rows per block; Wq (64 KB) + x rows (16 KB) in LDS
  __shared__ __align__(16) float wqs[256 * 64];
  __shared__ __align__(16) float xs[16 * 256];
  #pragma unroll 8
  for (int it = 0; it < 64; ++it)
    wqs[tid + it * 256] = Wq[tid + it * 256];
  int r0 = blockIdx.x * 16;
  #pragma unroll
  for (int it = 0; it < 16; ++it)
    xs[tid + it * 256] = x[(size_t)r0 * 256 + tid + it * 256];
  __syncthreads();
  int kd = tid & 63, rr = tid >> 6;     // 4 rows per pass, 4 passes
  #pragma unroll
  for (int rp = 0; rp < 4; ++rp) {
    int r = rp * 4 + rr;
    float a0 = bq[kd], a1 = 0.f, a2 = 0.f, a3 = 0.f;
    #pragma unroll 4
    for (int d = 0; d < 256; d += 4) {
      a0 = fmaf(xs[r * 256 + d],     wqs[(d)     * 64 + kd], a0);
      a1 = fmaf(xs[r * 256 + d + 1], wqs[(d + 1) * 64 + kd], a1);
      a2 = fmaf(xs[r * 256 + d + 2], wqs[(d + 2) * 64 + kd], a2);
      a3 = fmaf(xs[r * 256 + d + 3], wqs[(d + 3) * 64 + kd], a3);
    }
    Qh[(size_t)(r0 + r) * 64 + kd] = f2bf((a0 + a1) + (a2 + a3));
  }
}

// =====================================================================
// Single W-plane staging: row r (=kd) is 512 B = 32 16B-chunks,
// swizzle blk ^ (r&7). Fragment read: row f*16+c, chunk ks*4+g.
// =====================================================================
__device__ __forceinline__ void stage_plane(
    char* dstb, const unsigned short* __restrict__ Wt, int tid) {
  #pragma unroll
  for (int it = 0; it < 4; ++it) {
    int qq = tid + it * 512;            // 16B chunk id, 0..2047
    int r = qq >> 5, pb = qq & 31;
    uint4 v = *(const uint4*)((const char*)Wt + (size_t)qq * 16);
    *(uint4*)(dstb + r * 512 + ((pb ^ (r & 7)) << 4)) = v;
  }
}

// =====================================================================
// K2: FUSED per-(b,t), 64 KB LDS, 512 thr (8 waves), grid 512,
// 2 blocks/CU. R12/R14-verbatim except the R store layout:
// R is now [b][256 i][64 t][64 vd] (level-2 reads contiguous per (b,i)).
// =====================================================================
__global__ __launch_bounds__(512, 4) void k_fused(
    const float* __restrict__ Xm, const float* __restrict__ Ym,
    const unsigned short* __restrict__ Wkth, const unsigned short* __restrict__ Wvth,
    const float* __restrict__ bk, const float* __restrict__ bv,
    const unsigned short* __restrict__ Qh,
    unsigned short* __restrict__ R,      // [b][256 i][64 t][64 vd] bf16
    float* __restrict__ Sc) {            // [bt][256 i] raw row max
  __shared__ __align__(16) char smemb[65536];   // 64 KB
  int tid = threadIdx.x;
  int bt = blockIdx.x, b = bt >> 6, tmem = bt & 63;
  int w = tid >> 6, lane = tid & 63, c = lane & 15, g = lane >> 4;

  const float* xr0 = Xm + (size_t)bt * 65536 + (size_t)(w * 32 + c) * 256 + g * 8;
  const float* xr1 = xr0 + 16 * 256;
  const float* yr0 = Ym + (size_t)bt * 65536 + (size_t)(w * 32 + c) * 256 + g * 8;
  const float* yr1 = yr0 + 16 * 256;

  // ---- pre-issue chunks 0,1 of BOTH streams (fly during W staging) ----
  float4 xa0 = *(const float4*)(xr0),      xa1 = *(const float4*)(xr0 + 4);
  float4 xa2 = *(const float4*)(xr1),      xa3 = *(const float4*)(xr1 + 4);
  float4 xb0 = *(const float4*)(xr0 + 32), xb1 = *(const float4*)(xr0 + 36);
  float4 xb2 = *(const float4*)(xr1 + 32), xb3 = *(const float4*)(xr1 + 36);
  float4 ya0 = *(const float4*)(yr0),      ya1 = *(const float4*)(yr0 + 4);
  float4 ya2 = *(const float4*)(yr1),      ya3 = *(const float4*)(yr1 + 4);
  float4 yb0 = *(const float4*)(yr0 + 32), yb1 = *(const float4*)(yr0 + 36);
  float4 yb2 = *(const float4*)(yr1 + 32), yb3 = *(const float4*)(yr1 + 36);

  // ---- stage Wk-hi -> R1, Wv-hi -> R2 ----
  stage_plane(smemb, Wkth, tid);
  stage_plane(smemb + R2B, Wvth, tid);
  __syncthreads();                                   // barrier 1

  // ---------------- merged projection loop (8 k-steps) ------------------
  f32x4 kacc[4][2];   // K: M=kd (4 mf), N=j (2 nj)
  f32x4 vacc[2][4];   // V: M=j (2 mf), N=vd (4 nf)
  #pragma unroll
  for (int mf = 0; mf < 4; ++mf) { kacc[mf][0] = (f32x4)0.f; kacc[mf][1] = (f32x4)0.f; }
  #pragma unroll
  for (int mf = 0; mf < 2; ++mf)
    #pragma unroll
    for (int nf = 0; nf < 4; ++nf) vacc[mf][nf] = (f32x4)0.f;

  #pragma unroll
  for (int ks = 0; ks < 8; ++ks) {
    // ---- X part: consume slot, reload with chunk ks+2, K MFMAs ----
    float x0[8], x1[8];
    if (ks & 1) {
      *(float4*)&x0[0] = xb0; *(float4*)&x0[4] = xb1;
      *(float4*)&x1[0] = xb2; *(float4*)&x1[4] = xb3;
      if (ks < 6) {
        xb0 = *(const float4*)(xr0 + (ks + 2) * 32);
        xb1 = *(const float4*)(xr0 + (ks + 2) * 32 + 4);
        xb2 = *(const float4*)(xr1 + (ks + 2) * 32);
        xb3 = *(const float4*)(xr1 + (ks + 2) * 32 + 4);
      }
    } else {
      *(float4*)&x0[0] = xa0; *(float4*)&x0[4] = xa1;
      *(float4*)&x1[0] = xa2; *(float4*)&x1[4] = xa3;
      if (ks < 6) {
        xa0 = *(const float4*)(xr0 + (ks + 2) * 32);
        xa1 = *(const float4*)(xr0 + (ks + 2) * 32 + 4);
        xa2 = *(const float4*)(xr1 + (ks + 2) * 32);
        xa3 = *(const float4*)(xr1 + (ks + 2) * 32 + 4);
      }
    }
    {
      bf16x8 b0h, b0l, b1h, b1l;
      split8(x0, b0h, b0l);
      split8(x1, b1h, b1l);
      #pragma unroll
      for (int mf = 0; mf < 4; ++mf) {
        int r = mf * 16 + c;
        int ba = r * 512 + (((ks * 4 + g) ^ (r & 7)) << 4);
        bf16x8 awh = *(const bf16x8*)(smemb + ba);
        kacc[mf][0] = MFMA16(awh, b0h, kacc[mf][0]);
        kacc[mf][0] = MFMA16(awh, b0l, kacc[mf][0]);
        kacc[mf][1] = MFMA16(awh, b1h, kacc[mf][1]);
        kacc[mf][1] = MFMA16(awh, b1l, kacc[mf][1]);
      }
    }
    // ---- Y part: consume slot, reload with chunk ks+2, V MFMAs ----
    float y0[8], y1[8];
    if (ks & 1) {
      *(float4*)&y0[0] = yb0; *(float4*)&y0[4] = yb1;
      *(float4*)&y1[0] = yb2; *(float4*)&y1[4] = yb3;
      if (ks < 6) {
        yb0 = *(const float4*)(yr0 + (ks + 2) * 32);
        yb1 = *(const float4*)(yr0 + (ks + 2) * 32 + 4);
        yb2 = *(const float4*)(yr1 + (ks + 2) * 32);
        yb3 = *(const float4*)(yr1 + (ks + 2) * 32 + 4);
      }
    } else {
      *(float4*)&y0[0] = ya0; *(float4*)&y0[4] = ya1;
      *(float4*)&y1[0] = ya2; *(float4*)&y1[4] = ya3;
      if (ks < 6) {
        ya0 = *(const float4*)(yr0 + (ks + 2) * 32);
        ya1 = *(const float4*)(yr0 + (ks + 2) * 32 + 4);
        ya2 = *(const float4*)(yr1 + (ks + 2) * 32);
        ya3 = *(const float4*)(yr1 + (ks + 2) * 32 + 4);
      }
    }
    {
      bf16x8 a0h, a0l, a1h, a1l;
      split8(y0, a0h, a0l);
      split8(y1, a1h, a1l);
      #pragma unroll
      for (int nf = 0; nf < 4; ++nf) {
        int r = nf * 16 + c;
        int ba = R2B + r * 512 + (((ks * 4 + g) ^ (r & 7)) << 4);
        bf16x8 bwh = *(const bf16x8*)(smemb + ba);
        vacc[0][nf] = MFMA16(a0h, bwh, vacc[0][nf]);
        vacc[0][nf] = MFMA16(a0l, bwh, vacc[0][nf]);
        vacc[1][nf] = MFMA16(a1h, bwh, vacc[1][nf]);
        vacc[1][nf] = MFMA16(a1l, bwh, vacc[1][nf]);
      }
    }
  }
  // pre-issue Q frags (fly across the next two barriers)
  bf16x8 qbh[2][2];   // [ks][ic]
  #pragma unroll
  for (int ks = 0; ks < 2; ++ks)
    #pragma unroll
    for (int ic = 0; ic < 2; ++ic) {
      size_t qo = ((size_t)b * NI + w * 32 + ic * 16 + c) * NKD + ks * 32 + g * 8;
      qbh[ks][ic] = *(const bf16x8*)(Qh + qo);
    }
  __syncthreads();                                   // barrier 2 (W reads done)

  // ---- epilogues: K-hi -> R1 (over Wk), V-hi -> R2 (over Wv) ----
  #pragma unroll
  for (int nf = 0; nf < 2; ++nf) {
    int j = w * 32 + nf * 16 + c;
    #pragma unroll
    for (int mf = 0; mf < 4; ++mf) {   // element (kd = mf*16+4g+r, j)
      bf16x4 ph;
      #pragma unroll
      for (int r = 0; r < 4; ++r)
        ph[r] = (short)f2bf(kacc[mf][nf][r] + bk[mf * 16 + g * 4 + r]);
      int pb = mf * 2 + (g >> 1);
      int ba = j * 128 + ((pb ^ (j & 7)) << 4) + (g & 1) * 8;
      *(bf16x4*)(smemb + ba) = ph;
    }
  }
  #pragma unroll
  for (int nf = 0; nf < 4; ++nf) {
    int vd = nf * 16 + c;
    float bs = bv[vd];
    #pragma unroll
    for (int mf = 0; mf < 2; ++mf) {   // element (j = w*32+mf*16+4g+r, vd)
      bf16x4 ph;
      #pragma unroll
      for (int r = 0; r < 4; ++r) ph[r] = (short)f2bf(vacc[mf][nf][r] + bs);
      int pb = w * 4 + mf * 2 + (g >> 1);
      int ba = R2B + vd * 512 + ((pb ^ (vd & 7)) << 4) + (g & 1) * 8;
      *(bf16x4*)(smemb + ba) = ph;
    }
  }
  __syncthreads();                                   // barrier 3: LDS read-only now

  // ---------------- attention (wave w: i = w*32 .. +32) -----------------
  #pragma unroll
  for (int ic = 0; ic < 2; ++ic) {
    int i = w * 32 + ic * 16 + c;

    // S^T = K * Q^T (1 Q-term): sa[jf] holds S^T[j = 16jf+4g+r][i]
    f32x4 sa[16];
    #pragma unroll
    for (int jf = 0; jf < 16; ++jf) sa[jf] = (f32x4)0.f;
    #pragma unroll
    for (int jf = 0; jf < 16; ++jf) {
      int j = jf * 16 + c;
      #pragma unroll
      for (int ks = 0; ks < 2; ++ks) {
        int ba = j * 128 + (((ks * 4 + g) ^ (j & 7)) << 4);
        bf16x8 kh = *(const bf16x8*)(smemb + ba);
        sa[jf] = MFMA16(kh, qbh[ks][ic], sa[jf]);
      }
    }

    // softmax over j (lane-local + 2 shfl)
    float mx = sa[0][0];
    #pragma unroll
    for (int jf = 0; jf < 16; ++jf)
      #pragma unroll
      for (int r = 0; r < 4; ++r) mx = fmaxf(mx, sa[jf][r]);
    mx = fmaxf(mx, __shfl_xor(mx, 16));
    mx = fmaxf(mx, __shfl_xor(mx, 32));
    if (g == 0) Sc[(size_t)bt * NI + i] = mx;   // raw max
    float sum = 0.f;
    #pragma unroll
    for (int jf = 0; jf < 16; ++jf)
      #pragma unroll
      for (int r = 0; r < 4; ++r) {
        float p = __expf((sa[jf][r] - mx) * SCL);
        sa[jf][r] = p;
        sum += p;
      }
    sum += __shfl_xor(sum, 16);
    sum += __shfl_xor(sum, 32);
    float linv = 1.0f / sum;

    // pack P into bf16-pair words: plo/phi[jf] = j {16jf+4g+0,1}/{2,3}
    unsigned int plo[16], phi[16];
    #pragma unroll
    for (int jf = 0; jf < 16; ++jf) {
      plo[jf] = (unsigned int)f2bf(sa[jf][0]) | ((unsigned int)f2bf(sa[jf][1]) << 16);
      phi[jf] = (unsigned int)f2bf(sa[jf][2]) | ((unsigned int)f2bf(sa[jf][3]) << 16);
    }

    // in-register P^T redistribution (verified R4/R6..R14)
    int srcA = c + 32 * (g & 1);
    int srcB = srcA + 16;
    bool hiH = (g >= 2);

    f32x4 racc[4];
    #pragma unroll
    for (int vf = 0; vf < 4; ++vf) racc[vf] = (f32x4)0.f;
    #pragma unroll
    for (int js = 0; js < 8; ++js) {
      int a0 = __shfl((int)plo[2 * js], srcA);
      int a1 = __shfl((int)phi[2 * js], srcA);
      int a2 = __shfl((int)plo[2 * js], srcB);
      int a3 = __shfl((int)phi[2 * js], srcB);
      int b0 = __shfl((int)plo[2 * js + 1], srcA);
      int b1 = __shfl((int)phi[2 * js + 1], srcA);
      int b2 = __shfl((int)plo[2 * js + 1], srcB);
      int b3 = __shfl((int)phi[2 * js + 1], srcB);
      uint32x4 pw;
      pw[0] = (unsigned int)(hiH ? b0 : a0);
      pw[1] = (unsigned int)(hiH ? b1 : a1);
      pw[2] = (unsigned int)(hiH ? b2 : a2);
      pw[3] = (unsigned int)(hiH ? b3 : a3);
      bf16x8 pf = __builtin_bit_cast(bf16x8, pw);
      #pragma unroll
      for (int vf = 0; vf < 4; ++vf) {
        int vd = vf * 16 + c;
        int vba = R2B + vd * 512 + (((js * 4 + g) ^ (vd & 7)) << 4);
        bf16x8 vh = *(const bf16x8*)(smemb + vba);
        racc[vf] = MFMA16(vh, pf, racc[vf]);
      }
    }

    // write R[b][i][t][vd] bf16, normalized; element (vd = vf*16+4g+r, i)
    #pragma unroll
    for (int vf = 0; vf < 4; ++vf) {
      bf16x4 rk;
      #pragma unroll
      for (int r = 0; r < 4; ++r) rk[r] = (short)f2bf(racc[vf][r] * linv);
      *(bf16x4*)(R + (((size_t)b * NI + i) * NT + tmem) * NKD + vf * 16 + g * 4) = rk;
    }
  }
}

// =====================================================================
// K3: level-2 attention over t. 256 thr (4 waves), grid 512.
// Wave handles one (b,i). Phase A: lane = t computes softmax weight wn.
// Phase B: lane = (tg, vg): tg = lane>>3 covers t = tg*8..+8,
//   vg = lane&7 covers vd = vg*8..+8 via uint4 (8 bf16) loads from the
//   contiguous R[b][i][64 t][64 vd] slab; shfl_xor tree over tg (8,16,32);
//   tg==0 lanes write 8 vd each.
// =====================================================================
__global__ __launch_bounds__(256) void k_level2(
    const float* __restrict__ Sc,         // [bt][256]
    const unsigned short* __restrict__ R, // [b][256 i][64 t][64 vd] bf16
    float* __restrict__ out) {            // [b][256][64] f32
  int w = threadIdx.x >> 6, lane = threadIdx.x & 63;
  int bi = blockIdx.x * 4 + w;
  int b = bi >> 8, i = bi & 255;
  // ---- phase A: lane = t ----
  float sc = Sc[((size_t)b * NT + lane) * NI + i];
  float mx = sc;
  #pragma unroll
  for (int off = 32; off; off >>= 1) mx = fmaxf(mx, __shfl_xor(mx, off));
  float e = __expf((sc - mx) * SCL);
  float sum = e;
  #pragma unroll
  for (int off = 32; off; off >>= 1) sum += __shfl_xor(sum, off);
  float wn = e / sum;                  // weight for t = lane
  // ---- phase B: lane = (tg, vg) ----
  int tg = lane >> 3, vg = lane & 7;
  const unsigned short* rb = R + ((size_t)b * NI + i) * (NT * NKD);
  float acc[8];
  #pragma unroll
  for (int v8 = 0; v8 < 8; ++v8) acc[v8] = 0.f;
  #pragma unroll
  for (int tt = 0; tt < 8; ++tt) {
    int t = tg * 8 + tt;
    float wt = __shfl(wn, t);
    uint4 rv = *(const uint4*)(rb + (size_t)t * NKD + vg * 8);
    const unsigned short* rs = (const unsigned short*)&rv;
    #pragma unroll
    for (int v8 = 0; v8 < 8; ++v8) acc[v8] = fmaf(wt, bf2f(rs[v8]), acc[v8]);
  }
  // reduce over tg groups (lanes tg*8+vg, xor 8/16/32 preserves vg)
  #pragma unroll
  for (int v8 = 0; v8 < 8; ++v8) {
    float v = acc[v8];
    v += __shfl_xor(v, 8);
    v += __shfl_xor(v, 16);
    v += __shfl_xor(v, 32);
    acc[v8] = v;
  }
  if (tg == 0) {
    float* op = out + ((size_t)b * NI + i) * NVD + vg * 8;
    #pragma unroll
    for (int v8 = 0; v8 < 8; ++v8) op[v8] = acc[v8];
  }
}

// =====================================================================
extern "C" void kernel_launch(void* const* d_in, const int* in_sizes, int n_in,
                              void* d_out, int out_size, void* d_ws, size_t ws_size,
                              hipStream_t stream) {
  const float* x   = (const float*)d_in[0];
  const float* mxp = (const float*)d_in[1];
  const float* myp = (const float*)d_in[2];
  const float* Wq  = (const float*)d_in[3];
  const float* bq  = (const float*)d_in[4];
  const float* Wk  = (const float*)d_in[5];
  const float* bk  = (const float*)d_in[6];
  const float* Wv  = (const float*)d_in[7];
  const float* bv  = (const float*)d_in[8];
  float* out = (float*)d_out;

  // workspace carve (~18 MB)
  char* p = (char*)d_ws;
  auto alloc = [&](size_t bytes) { char* r = p; p += (bytes + 255) & ~(size_t)255; return r; };
  unsigned short* Qh   = (unsigned short*)alloc(2048 * 64 * 2);
  unsigned short* Rw   = (unsigned short*)alloc((size_t)131072 * 64 * 2);
  float*          Scw  = (float*)alloc((size_t)131072 * 4);
  unsigned short* Wkth = (unsigned short*)alloc(64 * 256 * 2);
  unsigned short* Wvth = (unsigned short*)alloc(64 * 256 * 2);

  hipLaunchKernelGGL(k_prep_projq, dim3(136), dim3(256), 0, stream,
                     x, Wq, bq, Wk, Wv, Wkth, Wvth, Qh);
  hipLaunchKernelGGL(k_fused, dim3(NB * NT), dim3(512), 0, stream,
                     mxp, myp, Wkth, Wvth, bk, bv, Qh, Rw, Scw);
  hipLaunchKernelGGL(k_level2, dim3(512), dim3(256), 0, stream, Scw, Rw, out);
}

// Round 16
// 85.382 us; speedup vs baseline: 1.2789x; 1.0072x over previous
//
#include <hip/hip_runtime.h>
#include <hip/hip_bf16.h>

// Shapes (fixed)
#define NB 8
#define NT 64
#define NI 256
#define NJ 256
#define ND 256
#define NKD 64
#define NVD 64
#define SCL 0.125f   // 1/sqrt(64), both attention levels

typedef __attribute__((ext_vector_type(4))) float f32x4;
typedef __attribute__((ext_vector_type(8))) short bf16x8;  // 8 bf16 = 4 VGPR (MFMA A/B frag)
typedef __attribute__((ext_vector_type(4))) short bf16x4;  // 4 bf16 = 8 B packed store
typedef __attribute__((ext_vector_type(4))) unsigned int uint32x4;

// D[16 M][16 N] = A[16 M][32 K] * B[32 K][16 N] + C
// A frag: lane l holds A[l%16][8*(l/16)+e] ; B frag: B[8*(l/16)+e][l%16]
// C/D:    lane l holds D[4*(l/16)+r][l%16]
#define MFMA16(A, B, C) __builtin_amdgcn_mfma_f32_16x16x32_bf16((A), (B), (C), 0, 0, 0)

// LDS overlay (64 KB total):
//   R1 [0,32K):    Wk-hi -> K-hi[256 j][64 kd]  (rows 128 B, blk^(j&7))
//   R2 [32K,64K):  Wv-hi -> V-hi[64 vd][256 j]  (rows 512 B, blk^(vd&7))
#define R2B 32768

__device__ __forceinline__ unsigned short f2bf(float x) {   // RNE
  return __builtin_bit_cast(unsigned short, __float2bfloat16(x));
}
__device__ __forceinline__ float bf2f(unsigned short h) {
  return __builtin_bit_cast(float, (unsigned)h << 16);
}
// split fp32 -> hi + lo bf16; hi+lo = x to ~2^-18 rel
__device__ __forceinline__ void split8(const float* __restrict__ x, bf16x8& hi, bf16x8& lo) {
  #pragma unroll
  for (int e = 0; e < 8; ++e) {
    unsigned short h = f2bf(x[e]);
    hi[e] = (short)h;
    lo[e] = (short)f2bf(x[e] - bf2f(h));
  }
}

// =====================================================================
// K1: Q-proj (blocks 0..127, 16 rows each, Wq staged in LDS) +
//     W-prep (blocks 128..135). 256 thr. (R14-verbatim)
// =====================================================================
__global__ __launch_bounds__(256) void k_prep_projq(
    const float* __restrict__ x, const float* __restrict__ Wq,
    const float* __restrict__ bq,
    const float* __restrict__ Wk, const float* __restrict__ Wv,
    unsigned short* __restrict__ Wkth, unsigned short* __restrict__ Wvth,
    unsigned short* __restrict__ Qh) {
  int tid = threadIdx.x;
  if (blockIdx.x >= 128) {              // prep weights (hi planes only)
    int t0 = (blockIdx.x - 128) * 2048 + tid * 8;
    #pragma unroll
    for (int e = 0; e < 8; ++e) {
      int t = t0 + e;
      int d = t >> 6, kd = t & 63;
      Wkth[kd * 256 + d] = f2bf(Wk[t]);
      Wvth[kd * 256 + d] = f2bf(Wv[t]);
    }
    return;
  }
  // Q-proj: 16 rows per block; Wq (64 KB) + x rows (16 KB) in LDS
  __shared__ __align__(16) float wqs[256 * 64];
  __shared__ __align__(16) float xs[16 * 256];
  #pragma unroll 8
  for (int it = 0; it < 64; ++it)
    wqs[tid + it * 256] = Wq[tid + it * 256];
  int r0 = blockIdx.x * 16;
  #pragma unroll
  for (int it = 0; it < 16; ++it)
    xs[tid + it * 256] = x[(size_t)r0 * 256 + tid + it * 256];
  __syncthreads();
  int kd = tid & 63, rr = tid >> 6;     // 4 rows per pass, 4 passes
  #pragma unroll
  for (int rp = 0; rp < 4; ++rp) {
    int r = rp * 4 + rr;
    float a0 = bq[kd], a1 = 0.f, a2 = 0.f, a3 = 0.f;
    #pragma unroll 4
    for (int d = 0; d < 256; d += 4) {
      a0 = fmaf(xs[r * 256 + d],     wqs[(d)     * 64 + kd], a0);
      a1 = fmaf(xs[r * 256 + d + 1], wqs[(d + 1) * 64 + kd], a1);
      a2 = fmaf(xs[r * 256 + d + 2], wqs[(d + 2) * 64 + kd], a2);
      a3 = fmaf(xs[r * 256 + d + 3], wqs[(d + 3) * 64 + kd], a3);
    }
    Qh[(size_t)(r0 + r) * 64 + kd] = f2bf((a0 + a1) + (a2 + a3));
  }
}

// =====================================================================
// Single W-plane staging: row r (=kd) is 512 B = 32 16B-chunks,
// swizzle blk ^ (r&7). Fragment read: row f*16+c, chunk ks*4+g.
// =====================================================================
__device__ __forceinline__ void stage_plane(
    char* dstb, const unsigned short* __restrict__ Wt, int tid) {
  #pragma unroll
  for (int it = 0; it < 4; ++it) {
    int qq = tid + it * 512;            // 16B chunk id, 0..2047
    int r = qq >> 5, pb = qq & 31;
    uint4 v = *(const uint4*)((const char*)Wt + (size_t)qq * 16);
    *(uint4*)(dstb + r * 512 + ((pb ^ (r & 7)) << 4)) = v;
  }
}

// =====================================================================
// K2: FUSED per-(b,t), 64 KB LDS, 512 thr (8 waves), grid 512,
// 2 blocks/CU. R15-verbatim except Sc layout: now [b][256 i][64 t]
// (level-2 phase-A reads become one contiguous 256 B segment/wave;
// scattered 4 B writes here are absorbed by the shared L3).
// =====================================================================
__global__ __launch_bounds__(512, 4) void k_fused(
    const float* __restrict__ Xm, const float* __restrict__ Ym,
    const unsigned short* __restrict__ Wkth, const unsigned short* __restrict__ Wvth,
    const float* __restrict__ bk, const float* __restrict__ bv,
    const unsigned short* __restrict__ Qh,
    unsigned short* __restrict__ R,      // [b][256 i][64 t][64 vd] bf16
    float* __restrict__ Sc) {            // [b][256 i][64 t] raw row max
  __shared__ __align__(16) char smemb[65536];   // 64 KB
  int tid = threadIdx.x;
  int bt = blockIdx.x, b = bt >> 6, tmem = bt & 63;
  int w = tid >> 6, lane = tid & 63, c = lane & 15, g = lane >> 4;

  const float* xr0 = Xm + (size_t)bt * 65536 + (size_t)(w * 32 + c) * 256 + g * 8;
  const float* xr1 = xr0 + 16 * 256;
  const float* yr0 = Ym + (size_t)bt * 65536 + (size_t)(w * 32 + c) * 256 + g * 8;
  const float* yr1 = yr0 + 16 * 256;

  // ---- pre-issue chunks 0,1 of BOTH streams (fly during W staging) ----
  float4 xa0 = *(const float4*)(xr0),      xa1 = *(const float4*)(xr0 + 4);
  float4 xa2 = *(const float4*)(xr1),      xa3 = *(const float4*)(xr1 + 4);
  float4 xb0 = *(const float4*)(xr0 + 32), xb1 = *(const float4*)(xr0 + 36);
  float4 xb2 = *(const float4*)(xr1 + 32), xb3 = *(const float4*)(xr1 + 36);
  float4 ya0 = *(const float4*)(yr0),      ya1 = *(const float4*)(yr0 + 4);
  float4 ya2 = *(const float4*)(yr1),      ya3 = *(const float4*)(yr1 + 4);
  float4 yb0 = *(const float4*)(yr0 + 32), yb1 = *(const float4*)(yr0 + 36);
  float4 yb2 = *(const float4*)(yr1 + 32), yb3 = *(const float4*)(yr1 + 36);

  // ---- stage Wk-hi -> R1, Wv-hi -> R2 ----
  stage_plane(smemb, Wkth, tid);
  stage_plane(smemb + R2B, Wvth, tid);
  __syncthreads();                                   // barrier 1

  // ---------------- merged projection loop (8 k-steps) ------------------
  f32x4 kacc[4][2];   // K: M=kd (4 mf), N=j (2 nj)
  f32x4 vacc[2][4];   // V: M=j (2 mf), N=vd (4 nf)
  #pragma unroll
  for (int mf = 0; mf < 4; ++mf) { kacc[mf][0] = (f32x4)0.f; kacc[mf][1] = (f32x4)0.f; }
  #pragma unroll
  for (int mf = 0; mf < 2; ++mf)
    #pragma unroll
    for (int nf = 0; nf < 4; ++nf) vacc[mf][nf] = (f32x4)0.f;

  #pragma unroll
  for (int ks = 0; ks < 8; ++ks) {
    // ---- X part: consume slot, reload with chunk ks+2, K MFMAs ----
    float x0[8], x1[8];
    if (ks & 1) {
      *(float4*)&x0[0] = xb0; *(float4*)&x0[4] = xb1;
      *(float4*)&x1[0] = xb2; *(float4*)&x1[4] = xb3;
      if (ks < 6) {
        xb0 = *(const float4*)(xr0 + (ks + 2) * 32);
        xb1 = *(const float4*)(xr0 + (ks + 2) * 32 + 4);
        xb2 = *(const float4*)(xr1 + (ks + 2) * 32);
        xb3 = *(const float4*)(xr1 + (ks + 2) * 32 + 4);
      }
    } else {
      *(float4*)&x0[0] = xa0; *(float4*)&x0[4] = xa1;
      *(float4*)&x1[0] = xa2; *(float4*)&x1[4] = xa3;
      if (ks < 6) {
        xa0 = *(const float4*)(xr0 + (ks + 2) * 32);
        xa1 = *(const float4*)(xr0 + (ks + 2) * 32 + 4);
        xa2 = *(const float4*)(xr1 + (ks + 2) * 32);
        xa3 = *(const float4*)(xr1 + (ks + 2) * 32 + 4);
      }
    }
    {
      bf16x8 b0h, b0l, b1h, b1l;
      split8(x0, b0h, b0l);
      split8(x1, b1h, b1l);
      #pragma unroll
      for (int mf = 0; mf < 4; ++mf) {
        int r = mf * 16 + c;
        int ba = r * 512 + (((ks * 4 + g) ^ (r & 7)) << 4);
        bf16x8 awh = *(const bf16x8*)(smemb + ba);
        kacc[mf][0] = MFMA16(awh, b0h, kacc[mf][0]);
        kacc[mf][0] = MFMA16(awh, b0l, kacc[mf][0]);
        kacc[mf][1] = MFMA16(awh, b1h, kacc[mf][1]);
        kacc[mf][1] = MFMA16(awh, b1l, kacc[mf][1]);
      }
    }
    // ---- Y part: consume slot, reload with chunk ks+2, V MFMAs ----
    float y0[8], y1[8];
    if (ks & 1) {
      *(float4*)&y0[0] = yb0; *(float4*)&y0[4] = yb1;
      *(float4*)&y1[0] = yb2; *(float4*)&y1[4] = yb3;
      if (ks < 6) {
        yb0 = *(const float4*)(yr0 + (ks + 2) * 32);
        yb1 = *(const float4*)(yr0 + (ks + 2) * 32 + 4);
        yb2 = *(const float4*)(yr1 + (ks + 2) * 32);
        yb3 = *(const float4*)(yr1 + (ks + 2) * 32 + 4);
      }
    } else {
      *(float4*)&y0[0] = ya0; *(float4*)&y0[4] = ya1;
      *(float4*)&y1[0] = ya2; *(float4*)&y1[4] = ya3;
      if (ks < 6) {
        ya0 = *(const float4*)(yr0 + (ks + 2) * 32);
        ya1 = *(const float4*)(yr0 + (ks + 2) * 32 + 4);
        ya2 = *(const float4*)(yr1 + (ks + 2) * 32);
        ya3 = *(const float4*)(yr1 + (ks + 2) * 32 + 4);
      }
    }
    {
      bf16x8 a0h, a0l, a1h, a1l;
      split8(y0, a0h, a0l);
      split8(y1, a1h, a1l);
      #pragma unroll
      for (int nf = 0; nf < 4; ++nf) {
        int r = nf * 16 + c;
        int ba = R2B + r * 512 + (((ks * 4 + g) ^ (r & 7)) << 4);
        bf16x8 bwh = *(const bf16x8*)(smemb + ba);
        vacc[0][nf] = MFMA16(a0h, bwh, vacc[0][nf]);
        vacc[0][nf] = MFMA16(a0l, bwh, vacc[0][nf]);
        vacc[1][nf] = MFMA16(a1h, bwh, vacc[1][nf]);
        vacc[1][nf] = MFMA16(a1l, bwh, vacc[1][nf]);
      }
    }
  }
  // pre-issue Q frags (fly across the next two barriers)
  bf16x8 qbh[2][2];   // [ks][ic]
  #pragma unroll
  for (int ks = 0; ks < 2; ++ks)
    #pragma unroll
    for (int ic = 0; ic < 2; ++ic) {
      size_t qo = ((size_t)b * NI + w * 32 + ic * 16 + c) * NKD + ks * 32 + g * 8;
      qbh[ks][ic] = *(const bf16x8*)(Qh + qo);
    }
  __syncthreads();                                   // barrier 2 (W reads done)

  // ---- epilogues: K-hi -> R1 (over Wk), V-hi -> R2 (over Wv) ----
  #pragma unroll
  for (int nf = 0; nf < 2; ++nf) {
    int j = w * 32 + nf * 16 + c;
    #pragma unroll
    for (int mf = 0; mf < 4; ++mf) {   // element (kd = mf*16+4g+r, j)
      bf16x4 ph;
      #pragma unroll
      for (int r = 0; r < 4; ++r)
        ph[r] = (short)f2bf(kacc[mf][nf][r] + bk[mf * 16 + g * 4 + r]);
      int pb = mf * 2 + (g >> 1);
      int ba = j * 128 + ((pb ^ (j & 7)) << 4) + (g & 1) * 8;
      *(bf16x4*)(smemb + ba) = ph;
    }
  }
  #pragma unroll
  for (int nf = 0; nf < 4; ++nf) {
    int vd = nf * 16 + c;
    float bs = bv[vd];
    #pragma unroll
    for (int mf = 0; mf < 2; ++mf) {   // element (j = w*32+mf*16+4g+r, vd)
      bf16x4 ph;
      #pragma unroll
      for (int r = 0; r < 4; ++r) ph[r] = (short)f2bf(vacc[mf][nf][r] + bs);
      int pb = w * 4 + mf * 2 + (g >> 1);
      int ba = R2B + vd * 512 + ((pb ^ (vd & 7)) << 4) + (g & 1) * 8;
      *(bf16x4*)(smemb + ba) = ph;
    }
  }
  __syncthreads();                                   // barrier 3: LDS read-only now

  // ---------------- attention (wave w: i = w*32 .. +32) -----------------
  #pragma unroll
  for (int ic = 0; ic < 2; ++ic) {
    int i = w * 32 + ic * 16 + c;

    // S^T = K * Q^T (1 Q-term): sa[jf] holds S^T[j = 16jf+4g+r][i]
    f32x4 sa[16];
    #pragma unroll
    for (int jf = 0; jf < 16; ++jf) sa[jf] = (f32x4)0.f;
    #pragma unroll
    for (int jf = 0; jf < 16; ++jf) {
      int j = jf * 16 + c;
      #pragma unroll
      for (int ks = 0; ks < 2; ++ks) {
        int ba = j * 128 + (((ks * 4 + g) ^ (j & 7)) << 4);
        bf16x8 kh = *(const bf16x8*)(smemb + ba);
        sa[jf] = MFMA16(kh, qbh[ks][ic], sa[jf]);
      }
    }

    // softmax over j (lane-local + 2 shfl)
    float mx = sa[0][0];
    #pragma unroll
    for (int jf = 0; jf < 16; ++jf)
      #pragma unroll
      for (int r = 0; r < 4; ++r) mx = fmaxf(mx, sa[jf][r]);
    mx = fmaxf(mx, __shfl_xor(mx, 16));
    mx = fmaxf(mx, __shfl_xor(mx, 32));
    if (g == 0) Sc[((size_t)b * NI + i) * NT + tmem] = mx;   // raw max, [b][i][t]
    float sum = 0.f;
    #pragma unroll
    for (int jf = 0; jf < 16; ++jf)
      #pragma unroll
      for (int r = 0; r < 4; ++r) {
        float p = __expf((sa[jf][r] - mx) * SCL);
        sa[jf][r] = p;
        sum += p;
      }
    sum += __shfl_xor(sum, 16);
    sum += __shfl_xor(sum, 32);
    float linv = 1.0f / sum;

    // pack P into bf16-pair words: plo/phi[jf] = j {16jf+4g+0,1}/{2,3}
    unsigned int plo[16], phi[16];
    #pragma unroll
    for (int jf = 0; jf < 16; ++jf) {
      plo[jf] = (unsigned int)f2bf(sa[jf][0]) | ((unsigned int)f2bf(sa[jf][1]) << 16);
      phi[jf] = (unsigned int)f2bf(sa[jf][2]) | ((unsigned int)f2bf(sa[jf][3]) << 16);
    }

    // in-register P^T redistribution (verified R4/R6..R15)
    int srcA = c + 32 * (g & 1);
    int srcB = srcA + 16;
    bool hiH = (g >= 2);

    f32x4 racc[4];
    #pragma unroll
    for (int vf = 0; vf < 4; ++vf) racc[vf] = (f32x4)0.f;
    #pragma unroll
    for (int js = 0; js < 8; ++js) {
      int a0 = __shfl((int)plo[2 * js], srcA);
      int a1 = __shfl((int)phi[2 * js], srcA);
      int a2 = __shfl((int)plo[2 * js], srcB);
      int a3 = __shfl((int)phi[2 * js], srcB);
      int b0 = __shfl((int)plo[2 * js + 1], srcA);
      int b1 = __shfl((int)phi[2 * js + 1], srcA);
      int b2 = __shfl((int)plo[2 * js + 1], srcB);
      int b3 = __shfl((int)phi[2 * js + 1], srcB);
      uint32x4 pw;
      pw[0] = (unsigned int)(hiH ? b0 : a0);
      pw[1] = (unsigned int)(hiH ? b1 : a1);
      pw[2] = (unsigned int)(hiH ? b2 : a2);
      pw[3] = (unsigned int)(hiH ? b3 : a3);
      bf16x8 pf = __builtin_bit_cast(bf16x8, pw);
      #pragma unroll
      for (int vf = 0; vf < 4; ++vf) {
        int vd = vf * 16 + c;
        int vba = R2B + vd * 512 + (((js * 4 + g) ^ (vd & 7)) << 4);
        bf16x8 vh = *(const bf16x8*)(smemb + vba);
        racc[vf] = MFMA16(vh, pf, racc[vf]);
      }
    }

    // write R[b][i][t][vd] bf16, normalized; element (vd = vf*16+4g+r, i)
    #pragma unroll
    for (int vf = 0; vf < 4; ++vf) {
      bf16x4 rk;
      #pragma unroll
      for (int r = 0; r < 4; ++r) rk[r] = (short)f2bf(racc[vf][r] * linv);
      *(bf16x4*)(R + (((size_t)b * NI + i) * NT + tmem) * NKD + vf * 16 + g * 4) = rk;
    }
  }
}

// =====================================================================
// K3: level-2 attention over t. 256 thr (4 waves), grid 512.
// Wave handles one (b,i). Phase A: lane = t, Sc read now CONTIGUOUS
// (256 B per wave). Phase B: lane = (tg, vg), uint4 R loads, shfl tree.
// =====================================================================
__global__ __launch_bounds__(256) void k_level2(
    const float* __restrict__ Sc,         // [b][256 i][64 t]
    const unsigned short* __restrict__ R, // [b][256 i][64 t][64 vd] bf16
    float* __restrict__ out) {            // [b][256][64] f32
  int w = threadIdx.x >> 6, lane = threadIdx.x & 63;
  int bi = blockIdx.x * 4 + w;
  int b = bi >> 8, i = bi & 255;
  // ---- phase A: lane = t (coalesced 256 B read) ----
  float sc = Sc[((size_t)b * NI + i) * NT + lane];
  float mx = sc;
  #pragma unroll
  for (int off = 32; off; off >>= 1) mx = fmaxf(mx, __shfl_xor(mx, off));
  float e = __expf((sc - mx) * SCL);
  float sum = e;
  #pragma unroll
  for (int off = 32; off; off >>= 1) sum += __shfl_xor(sum, off);
  float wn = e / sum;                  // weight for t = lane
  // ---- phase B: lane = (tg, vg) ----
  int tg = lane >> 3, vg = lane & 7;
  const unsigned short* rb = R + ((size_t)b * NI + i) * (NT * NKD);
  float acc[8];
  #pragma unroll
  for (int v8 = 0; v8 < 8; ++v8) acc[v8] = 0.f;
  #pragma unroll
  for (int tt = 0; tt < 8; ++tt) {
    int t = tg * 8 + tt;
    float wt = __shfl(wn, t);
    uint4 rv = *(const uint4*)(rb + (size_t)t * NKD + vg * 8);
    const unsigned short* rs = (const unsigned short*)&rv;
    #pragma unroll
    for (int v8 = 0; v8 < 8; ++v8) acc[v8] = fmaf(wt, bf2f(rs[v8]), acc[v8]);
  }
  // reduce over tg groups (lanes tg*8+vg, xor 8/16/32 preserves vg)
  #pragma unroll
  for (int v8 = 0; v8 < 8; ++v8) {
    float v = acc[v8];
    v += __shfl_xor(v, 8);
    v += __shfl_xor(v, 16);
    v += __shfl_xor(v, 32);
    acc[v8] = v;
  }
  if (tg == 0) {
    float* op = out + ((size_t)b * NI + i) * NVD + vg * 8;
    #pragma unroll
    for (int v8 = 0; v8 < 8; ++v8) op[v8] = acc[v8];
  }
}

// =====================================================================
extern "C" void kernel_launch(void* const* d_in, const int* in_sizes, int n_in,
                              void* d_out, int out_size, void* d_ws, size_t ws_size,
                              hipStream_t stream) {
  const float* x   = (const float*)d_in[0];
  const float* mxp = (const float*)d_in[1];
  const float* myp = (const float*)d_in[2];
  const float* Wq  = (const float*)d_in[3];
  const float* bq  = (const float*)d_in[4];
  const float* Wk  = (const float*)d_in[5];
  const float* bk  = (const float*)d_in[6];
  const float* Wv  = (const float*)d_in[7];
  const float* bv  = (const float*)d_in[8];
  float* out = (float*)d_out;

  // workspace carve (~18 MB)
  char* p = (char*)d_ws;
  auto alloc = [&](size_t bytes) { char* r = p; p += (bytes + 255) & ~(size_t)255; return r; };
  unsigned short* Qh   = (unsigned short*)alloc(2048 * 64 * 2);
  unsigned short* Rw   = (unsigned short*)alloc((size_t)131072 * 64 * 2);
  float*          Scw  = (float*)alloc((size_t)131072 * 4);
  unsigned short* Wkth = (unsigned short*)alloc(64 * 256 * 2);
  unsigned short* Wvth = (unsigned short*)alloc(64 * 256 * 2);

  hipLaunchKernelGGL(k_prep_projq, dim3(136), dim3(256), 0, stream,
                     x, Wq, bq, Wk, Wv, Wkth, Wvth, Qh);
  hipLaunchKernelGGL(k_fused, dim3(NB * NT), dim3(512), 0, stream,
                     mxp, myp, Wkth, Wvth, bk, bv, Qh, Rw, Scw);
  hipLaunchKernelGGL(k_level2, dim3(512), dim3(256), 0, stream, Scw, Rw, out);
}